// Round 5
// baseline (138.241 us; speedup 1.0000x reference)
//
#include <hip/hip_runtime.h>
#include <hip/hip_bf16.h>

// ============================================================================
// ROUND 5 = TIMING-DECOMPOSITION PROBE. Identical to round-4 kernel, but gemm
// is launched 4x (idempotent after init+bucket). dur5 = dur4 + 3*G + 3*eps
// isolates gemm's true cost G, since rocprof top-5 is occupied by harness
// fills and per-kernel counters are invisible. Revert to 1x next round.
// ============================================================================

// Problem constants (from reference)
#define BATCH   8192
#define NGRP    8
#define MAXGS   64
#define DMODEL  2048
#define TILES   512       // worst-case 16-row tiles per group (BATCH/16)
#define SPLITK  4         // waves per block; each owns 1/4 of each K chunk
#define KC      512       // K elements staged per chunk
#define NCHUNK  (DMODEL / KC)   // 4

typedef __attribute__((ext_vector_type(8))) short  short8;
typedef __attribute__((ext_vector_type(4))) float  f32x4;

// ws layout:
//   [0, 512)                     int cnt[8*16]  (each counter on its own 64B line)
//   [1024, 1024 + 8*8192*4)      int lists[8][8192]
//   [W_OFF, W_OFF + 1M*2)        ushort Wb[8][64][2048]  (bf16)
#define LISTS_OFF 1024
#define W_OFF (LISTS_OFF + NGRP * BATCH * 4)
#define CNT_STRIDE 16   // ints; 64B line per counter

static __device__ __forceinline__ short bf(float f) {
    // native f32->bf16 RNE; compiler pairs these into v_cvt_pk_bf16_f32
    __hip_bfloat16 h = __float2bfloat16(f);
    return (short)__bfloat16_as_ushort(h);
}

// async global->LDS DMA, 16B per lane; dest = wave-uniform base + lane*16
static __device__ __forceinline__ void gload_lds16(const float* src, float* lds) {
    __builtin_amdgcn_global_load_lds(
        (const __attribute__((address_space(1))) unsigned int*)src,
        (__attribute__((address_space(3))) unsigned int*)lds,
        16, 0, 0);
}

// Phase 0: zero padded group counters + convert W (f32 -> bf16) into ws.
__global__ __launch_bounds__(256) void init_kernel(const float* __restrict__ W,
                                                   unsigned short* __restrict__ Wb,
                                                   int* __restrict__ cnt) {
    int idx = blockIdx.x * 256 + threadIdx.x;
    if (idx < NGRP * CNT_STRIDE) cnt[idx] = 0;
    int e = idx * 4;
    float4 w = *reinterpret_cast<const float4*>(W + e);
    ushort4 o;
    o.x = (unsigned short)bf(w.x); o.y = (unsigned short)bf(w.y);
    o.z = (unsigned short)bf(w.z); o.w = (unsigned short)bf(w.w);
    *reinterpret_cast<ushort4*>(Wb + e) = o;
}

// Phase 1: bucket samples by chosen group (LDS-aggregated atomics).
// List order nondeterministic; per-sample output values are order-independent.
__global__ __launch_bounds__(256) void bucket_kernel(const int* __restrict__ chosen,
                                                     int* __restrict__ cnt,
                                                     int* __restrict__ lists) {
    __shared__ int lcnt[NGRP];
    __shared__ int lbase[NGRP];
    int tid = threadIdx.x;
    int b = blockIdx.x * 256 + tid;          // BATCH == 32*256 exactly
    int g = chosen[b];
    int lane = tid & 63;
    if (tid < NGRP) lcnt[tid] = 0;
    __syncthreads();

    int wbase = 0;
    unsigned long long mymask = 0;
    #pragma unroll
    for (int gg = 0; gg < NGRP; ++gg) {
        unsigned long long m = __ballot(g == gg);
        if (g == gg) {
            int leader = __ffsll(m) - 1;
            int wb_ = 0;
            if (lane == leader) wb_ = atomicAdd(&lcnt[gg], __popcll(m));
            wb_ = __shfl(wb_, leader);
            wbase = wb_;
            mymask = m;
        }
    }
    __syncthreads();
    if (tid < NGRP) lbase[tid] = atomicAdd(&cnt[tid * CNT_STRIDE], lcnt[tid]);
    __syncthreads();

    int pos = lbase[g] + wbase + __popcll(mymask & ((1ull << lane) - 1ull));
    lists[g * BATCH + pos] = b;
}

// Phase 2: per-group GEMM with LDS-staged A (identical to round 4).
__global__ __launch_bounds__(256, 3) void gemm_kernel(
    const float* __restrict__ hidden,
    const float* __restrict__ bias,
    const int* __restrict__ gsizes,
    const int* __restrict__ cnt,
    const int* __restrict__ lists,
    const unsigned short* __restrict__ Wb,
    float* __restrict__ out)
{
    int bid = blockIdx.x;
    int g = bid & (NGRP - 1);
    int t = bid >> 3;
    int c = cnt[g * CNT_STRIDE];
    int m0 = t << 4;
    if (m0 >= c) return;           // empty tile: whole block exits (uniform)

    union Smem {
        float A[16][KC];                 // 32 KB staged A chunk
        float red[SPLITK][64][17];       // 17.4 KB, used after last chunk
    };
    __shared__ Smem sm;

    int tid  = threadIdx.x;
    int w    = tid >> 6;           // wave id 0..3
    int lane = tid & 63;
    int lrow = lane & 15;
    int kg   = lane >> 4;          // 0..3

    // Each wave stages rows w*4 .. w*4+3. Gather their global row bases.
    const float* hbase[4];
    #pragma unroll
    for (int i = 0; i < 4; ++i) {
        int m  = m0 + w * 4 + i;
        int ms = m < c ? m : c - 1;          // tail: duplicate last row (harmless)
        int smp = lists[g * BATCH + ms];
        hbase[i] = hidden + ((size_t)smp * NGRP + g) * DMODEL;
    }

    f32x4 acc[4] = {f32x4{0,0,0,0}, f32x4{0,0,0,0}, f32x4{0,0,0,0}, f32x4{0,0,0,0}};
    int swr = (lrow & 7) << 4;     // read-side XOR swizzle for this lane's row

    for (int ch = 0; ch < NCHUNK; ++ch) {
        // ---- stage: 4 rows x 2KB per wave, 1KB contiguous per instruction ----
        #pragma unroll
        for (int i = 0; i < 4; ++i) {
            int r  = w * 4 + i;
            int sw = (r & 7) << 4;
            const float* src = hbase[i] + ch * KC;
            #pragma unroll
            for (int h = 0; h < 2; ++h) {
                int lb = (h * 1024 + lane * 16) ^ sw;   // bytes; XOR stays in-row
                gload_lds16(src + (lb >> 2), &sm.A[r][h * 256]);
            }
        }
        __syncthreads();

        // ---- compute: wave w owns k in [w*128, w*128+128) of this chunk ----
        #pragma unroll
        for (int kk = 0; kk < 4; ++kk) {
            int xb = w * 512 + kk * 128 + kg * 32;      // byte offset within row
            const char* arow = (const char*)&sm.A[lrow][0];
            f32x4 alo = *reinterpret_cast<const f32x4*>(arow + ((xb) ^ swr));
            f32x4 ahi = *reinterpret_cast<const f32x4*>(arow + ((xb + 16) ^ swr));
            short8 af;
            af[0] = bf(alo[0]); af[1] = bf(alo[1]); af[2] = bf(alo[2]); af[3] = bf(alo[3]);
            af[4] = bf(ahi[0]); af[5] = bf(ahi[1]); af[6] = bf(ahi[2]); af[7] = bf(ahi[3]);

            int kglob = ch * KC + w * 128 + kk * 32 + kg * 8;
            const unsigned short* wbp = Wb + ((size_t)g * MAXGS + lrow) * DMODEL + kglob;
            short8 b0 = *reinterpret_cast<const short8*>(wbp);
            short8 b1 = *reinterpret_cast<const short8*>(wbp + 16 * DMODEL);
            short8 b2 = *reinterpret_cast<const short8*>(wbp + 32 * DMODEL);
            short8 b3 = *reinterpret_cast<const short8*>(wbp + 48 * DMODEL);
            acc[0] = __builtin_amdgcn_mfma_f32_16x16x32_bf16(af, b0, acc[0], 0, 0, 0);
            acc[1] = __builtin_amdgcn_mfma_f32_16x16x32_bf16(af, b1, acc[1], 0, 0, 0);
            acc[2] = __builtin_amdgcn_mfma_f32_16x16x32_bf16(af, b2, acc[2], 0, 0, 0);
            acc[3] = __builtin_amdgcn_mfma_f32_16x16x32_bf16(af, b3, acc[3], 0, 0, 0);
        }
        __syncthreads();
    }

    // ---- split-K reduce (red overlays A; all A reads are behind the barrier) ----
    #pragma unroll
    for (int ti = 0; ti < 4; ++ti)
        #pragma unroll
        for (int r = 0; r < 4; ++r)
            sm.red[w][lane][ti * 4 + r] = acc[ti][r];
    __syncthreads();

    int gsz = gsizes[g];
    #pragma unroll
    for (int i = 0; i < 4; ++i) {
        int o  = tid + i * 256;        // 0..1023 = (m_local, n)
        int ml = o >> 6;
        int n  = o & 63;
        int rl = ((ml >> 2) << 4) | (n & 15);   // source lane
        int e  = ((n >> 4) << 2) | (ml & 3);    // acc element index
        float s = sm.red[0][rl][e] + sm.red[1][rl][e]
                + sm.red[2][rl][e] + sm.red[3][rl][e];
        int m = m0 + ml;
        if (m < c) {
            int smp = lists[g * BATCH + m];
            out[(size_t)smp * MAXGS + n] = s + bias[g * MAXGS + n];
            out[(size_t)(BATCH + smp) * MAXGS + n] = (n < gsz) ? 1.0f : 0.0f;
        }
    }
}

extern "C" void kernel_launch(void* const* d_in, const int* in_sizes, int n_in,
                              void* d_out, int out_size, void* d_ws, size_t ws_size,
                              hipStream_t stream) {
    const float* hidden = (const float*)d_in[0];   // [8192, 8, 2048] f32
    const int*   chosen = (const int*)d_in[1];     // [8192] i32
    const float* W      = (const float*)d_in[2];   // [8, 64, 2048] f32 (zero-padded)
    const float* bias   = (const float*)d_in[3];   // [8, 64] f32 (zero-padded)
    const int*   gs     = (const int*)d_in[4];     // [8] i32
    float* out = (float*)d_out;                    // [8192*64 preds | 8192*64 valid]

    char* ws = (char*)d_ws;
    int* cnt   = (int*)ws;
    int* lists = (int*)(ws + LISTS_OFF);
    unsigned short* Wb = (unsigned short*)(ws + W_OFF);

    init_kernel<<<dim3(1024), dim3(256), 0, stream>>>(W, Wb, cnt);
    bucket_kernel<<<dim3(32), dim3(256), 0, stream>>>(chosen, cnt, lists);
    // PROBE: 4x identical gemm launches (idempotent). dur = base + 3*G + 3*eps.
    gemm_kernel<<<dim3(NGRP * TILES), dim3(256), 0, stream>>>(
        hidden, bias, gs, cnt, lists, Wb, out);
    gemm_kernel<<<dim3(NGRP * TILES), dim3(256), 0, stream>>>(
        hidden, bias, gs, cnt, lists, Wb, out);
    gemm_kernel<<<dim3(NGRP * TILES), dim3(256), 0, stream>>>(
        hidden, bias, gs, cnt, lists, Wb, out);
    gemm_kernel<<<dim3(NGRP * TILES), dim3(256), 0, stream>>>(
        hidden, bias, gs, cnt, lists, Wb, out);
}